// Round 1
// baseline (498.554 us; speedup 1.0000x reference)
//
#include <hip/hip_runtime.h>
#include <stdint.h>

#define N_TOK    16384
#define E_DIM    256
#define N_CODE   5120
#define N_SHARED 2048
#define BIGF     1e7f

#define BM  256
#define BN  256
#define BK  32
#define NCB (N_CODE / BN)           // 20 column blocks
#define NKT (E_DIM / BK)            // 8 K-tiles
#define CHUNK (BM * BK)             // 8192 shorts = 16 KB per stream per K-tile

#define IDX_OFF ((size_t)N_TOK * E_DIM)                    // 4194304
#define D_OFF   (IDX_OFF + N_TOK)                          // 4210688
#define QL_OFF  (D_OFF + (size_t)N_TOK * N_CODE)           // 88096768

typedef float f32x4 __attribute__((ext_vector_type(4)));
typedef short bf16x8 __attribute__((ext_vector_type(8)));
typedef short s16x4 __attribute__((ext_vector_type(4)));

typedef __attribute__((address_space(1))) const unsigned int g_u32;
typedef __attribute__((address_space(3))) unsigned int lds_u32;

#define VMW(n) asm volatile("s_waitcnt vmcnt(" #n ")" ::: "memory")

__device__ __forceinline__ unsigned short bf16_rn(float f) {
    unsigned u = __float_as_uint(f);
    u += 0x7FFF + ((u >> 16) & 1);          // round-to-nearest-even
    return (unsigned short)(u >> 16);
}
__device__ __forceinline__ float bf16_to_f(unsigned short h) {
    return __uint_as_float(((unsigned)h) << 16);
}

// ---------------- K0: convert to hi/lo bf16 (fragment-swizzled, 256-row tiles) + row norms ----------------
// layout: [tile(256rows)][kt(8)][quad(4)][row(256)][8] -> linear global_load_lds staging
__global__ __launch_bounds__(256) void convert_kernel(const float* __restrict__ x,
                                                      const float* __restrict__ emb,
                                                      float* __restrict__ xx,
                                                      float* __restrict__ ee,
                                                      short* __restrict__ xhi, short* __restrict__ xlo,
                                                      short* __restrict__ ehi, short* __restrict__ elo) {
    int wid = threadIdx.x >> 6, ln = threadIdx.x & 63;
    int row = blockIdx.x * 4 + wid;             // 0 .. 21503
    const float* src; float* nrm; short *hiA, *loA; int rl, tb;
    if (row < N_TOK) {
        src = x + (size_t)row * E_DIM; nrm = xx + row;
        tb = row >> 8; rl = row & 255; hiA = xhi; loA = xlo;
    } else {
        int r = row - N_TOK;
        src = emb + (size_t)r * E_DIM; nrm = ee + r;
        tb = r >> 8; rl = r & 255; hiA = ehi; loA = elo;
    }
    f32x4 v = ((const f32x4*)src)[ln];          // k = ln*4 .. ln*4+3
    float s = v[0]*v[0] + v[1]*v[1] + v[2]*v[2] + v[3]*v[3];
    s16x4 h, l;
#pragma unroll
    for (int c = 0; c < 4; ++c) {
        unsigned short hh = bf16_rn(v[c]);
        h[c] = (short)hh;
        l[c] = (short)bf16_rn(v[c] - bf16_to_f(hh));
    }
    int kt = ln >> 3, q = (ln >> 1) & 3, kl4 = (ln & 1) * 4;
    size_t di = ((((size_t)tb * NKT + kt) * 4 + q) * BM + rl) * 8 + kl4;
    *(s16x4*)&hiA[di] = h;
    *(s16x4*)&loA[di] = l;
#pragma unroll
    for (int sh = 32; sh; sh >>= 1) s += __shfl_xor(s, sh, 64);
    if (ln == 0) *nrm = s;
}

// ---------------- K1: distance GEMM (256x256, counted-vmcnt pipeline) + mask + per-block argmin ----------------
__global__ __launch_bounds__(512, 2) void gemm_kernel(const short* __restrict__ xhi,
                                                      const short* __restrict__ xlo,
                                                      const short* __restrict__ ehi,
                                                      const short* __restrict__ elo,
                                                      const int* __restrict__ split,
                                                      const float* __restrict__ xx,
                                                      const float* __restrict__ ee,
                                                      float* __restrict__ out,
                                                      float* __restrict__ pmin,
                                                      int*   __restrict__ pidx) {
    __shared__ short Ah[2][CHUNK], Bh[2][CHUNK];   // unit U0 (hi), double-buffered
    __shared__ short Al[2][CHUNK], Bl[2][CHUNK];   // unit U1 (lo), double-buffered
    __shared__ float xxs[BM];
    __shared__ float ees[BN];
    __shared__ float redv[4][BM];
    __shared__ int   redi[4][BM];

    const int bx = blockIdx.x;      // code block 0..19
    const int by = blockIdx.y;      // token block 0..63
    const int m0 = by * BM, n0 = bx * BN;
    const int t = threadIdx.x;

    const int s1 = split[1], s2v = split[2];
    const int tmFirst = (m0 >= s1) + (m0 >= s2v);
    const int tmLast  = ((m0 + BM - 1) >= s1) + ((m0 + BM - 1) >= s2v);
    const bool rowUni = (tmFirst == tmLast);
    const int cmod = (n0 < N_SHARED) ? -1 : ((n0 - N_SHARED) >> 10);

    float* dOut = out + D_OFF;

    // fully-masked block: pure BIG fill, no GEMM
    if (cmod >= 0 && rowUni && cmod != tmFirst) {
        int row = t >> 1, half = t & 1;
        f32x4* p = (f32x4*)(dOut + (size_t)(m0 + row) * N_CODE + n0 + half * 128);
        f32x4 big = {BIGF, BIGF, BIGF, BIGF};
#pragma unroll
        for (int u = 0; u < 32; ++u) p[u] = big;
        if (t < BM) {
            pmin[(size_t)(m0 + t) * NCB + bx] = BIGF;
            pidx[(size_t)(m0 + t) * NCB + bx] = n0;
        }
        return;
    }

    const bool allAllowed = (cmod < 0) || (rowUni && cmod == tmFirst);

    if (t < BM) xxs[t] = xx[m0 + t];
    else        ees[t - BM] = ee[n0 + (t - BM)];
    __syncthreads();                // drain xx/ee loads (vmcnt 0) so manual counts see staging only

    f32x4 acc[8][4] = {};

    const int wid = t >> 6, lane = t & 63;
    const int quad = lane >> 4, ln16 = lane & 15;
    const int wr = (wid >> 2) * 128, wc = (wid & 3) * 64;
    const int qb = quad * BM;

    const short* aHiG = xhi + (size_t)by * NKT * CHUNK;
    const short* aLoG = xlo + (size_t)by * NKT * CHUNK;
    const short* bHiG = ehi + (size_t)bx * NKT * CHUNK;
    const short* bLoG = elo + (size_t)bx * NKT * CHUNK;
    const int tOff = t * 8;                     // shorts (16 B per thread per round)

    auto stageU0 = [&](int kt, int b) {         // 4 glds: Ah, Bh
        const size_t co = (size_t)kt * CHUNK;
#pragma unroll
        for (int p = 0; p < 2; ++p) {
            int o = p * 4096 + tOff;
            __builtin_amdgcn_global_load_lds((g_u32*)(aHiG + co + o), (lds_u32*)&Ah[b][o], 16, 0, 0);
            __builtin_amdgcn_global_load_lds((g_u32*)(bHiG + co + o), (lds_u32*)&Bh[b][o], 16, 0, 0);
        }
    };
    auto stageU1 = [&](int kt, int b) {         // 4 glds: Al, Bl
        const size_t co = (size_t)kt * CHUNK;
#pragma unroll
        for (int p = 0; p < 2; ++p) {
            int o = p * 4096 + tOff;
            __builtin_amdgcn_global_load_lds((g_u32*)(aLoG + co + o), (lds_u32*)&Al[b][o], 16, 0, 0);
            __builtin_amdgcn_global_load_lds((g_u32*)(bLoG + co + o), (lds_u32*)&Bl[b][o], 16, 0, 0);
        }
    };

    // prologue: U0(0), U1(0), U0(1) in flight (12 vmem ops)
    stageU0(0, 0); stageU1(0, 0); stageU0(1, 1);
    int cur = 0;

    // Per tile: phase A needs U0(t) -> wait leaving {U1(t), U0(t+1)} = 8 in flight.
    //           phase B needs U1(t) -> wait leaving {U0(t+1), U1(t+1)} = 8 in flight.
    // vmcnt hits 0 only in the final tile.
#define TILE(VA, VB, DOU1, DOU2, KT)                                                         \
    {                                                                                        \
        VMW(VA);                                                                             \
        __builtin_amdgcn_s_barrier();                                                        \
        if (DOU1) stageU1((KT) + 1, cur ^ 1);                                                \
        bf16x8 ah[8], bh[4];                                                                 \
        _Pragma("unroll") for (int i = 0; i < 8; ++i)                                        \
            ah[i] = *(const bf16x8*)&Ah[cur][(qb + wr + i * 16 + ln16) * 8];                 \
        _Pragma("unroll") for (int j = 0; j < 4; ++j)                                        \
            bh[j] = *(const bf16x8*)&Bh[cur][(qb + wc + j * 16 + ln16) * 8];                 \
        __builtin_amdgcn_s_setprio(1);                                                       \
        _Pragma("unroll") for (int i = 0; i < 8; ++i)                                        \
            _Pragma("unroll") for (int j = 0; j < 4; ++j)                                    \
                acc[i][j] = __builtin_amdgcn_mfma_f32_16x16x32_bf16(ah[i], bh[j], acc[i][j], 0, 0, 0); \
        __builtin_amdgcn_s_setprio(0);                                                       \
        VMW(VB);                                                                             \
        __builtin_amdgcn_s_barrier();                                                        \
        if (DOU2) stageU0((KT) + 2, cur);                                                    \
        bf16x8 bl[4];                                                                        \
        _Pragma("unroll") for (int j = 0; j < 4; ++j)                                        \
            bl[j] = *(const bf16x8*)&Bl[cur][(qb + wc + j * 16 + ln16) * 8];                 \
        __builtin_amdgcn_s_setprio(1);                                                       \
        _Pragma("unroll") for (int i = 0; i < 8; ++i)                                        \
            _Pragma("unroll") for (int j = 0; j < 4; ++j)                                    \
                acc[i][j] = __builtin_amdgcn_mfma_f32_16x16x32_bf16(ah[i], bl[j], acc[i][j], 0, 0, 0); \
        __builtin_amdgcn_s_setprio(0);                                                       \
        bf16x8 al[8];                                                                        \
        _Pragma("unroll") for (int i = 0; i < 8; ++i)                                        \
            al[i] = *(const bf16x8*)&Al[cur][(qb + wr + i * 16 + ln16) * 8];                 \
        __builtin_amdgcn_s_setprio(1);                                                       \
        _Pragma("unroll") for (int i = 0; i < 8; ++i)                                        \
            _Pragma("unroll") for (int j = 0; j < 4; ++j)                                    \
                acc[i][j] = __builtin_amdgcn_mfma_f32_16x16x32_bf16(al[i], bh[j], acc[i][j], 0, 0, 0); \
        __builtin_amdgcn_s_setprio(0);                                                       \
        cur ^= 1;                                                                            \
    }

    for (int kt = 0; kt < NKT - 2; ++kt)
        TILE(8, 8, true, true, kt);
    TILE(8, 8, true, false, NKT - 2);
    TILE(4, 0, false, false, NKT - 1);
#undef TILE

    // epilogue: d = xx + ee - 2*dot, mask, store, row-argmin over this block
#pragma unroll
    for (int i = 0; i < 8; ++i) {
#pragma unroll
        for (int r = 0; r < 4; ++r) {
            int lm = wr + i * 16 + quad * 4 + r;     // local row (C/D: row = quad*4+reg)
            int gm = m0 + lm;
            float xv = xxs[lm];
            int tmod = (gm >= s1) + (gm >= s2v);
            float best = 3.4e38f;
            int bidx = n0;
#pragma unroll
            for (int j = 0; j < 4; ++j) {
                int lnn = wc + j * 16 + ln16;        // local col (C/D: col = lane&15)
                int gn = n0 + lnn;
                float dv = fmaf(-2.f, acc[i][j][r], xv + ees[lnn]);
                if (!allAllowed) {
                    bool ok = (gn < N_SHARED) || (((gn - N_SHARED) >> 10) == tmod);
                    if (!ok) dv = BIGF;
                }
                dOut[(size_t)gm * N_CODE + gn] = dv;
                if (dv < best) { best = dv; bidx = gn; }   // j ascending: ties keep lowest gn
            }
#pragma unroll
            for (int s = 1; s < 16; s <<= 1) {
                float ov = __shfl_xor(best, s, 64);
                int   oi = __shfl_xor(bidx, s, 64);
                if (ov < best || (ov == best && oi < bidx)) { best = ov; bidx = oi; }
            }
            if (ln16 == 0) { redv[wid & 3][lm] = best; redi[wid & 3][lm] = bidx; }
        }
    }
    __syncthreads();
    if (t < BM) {
        float v0 = redv[0][t]; int i0 = redi[0][t];
#pragma unroll
        for (int w = 1; w < 4; ++w) {
            float v = redv[w][t]; int ii = redi[w][t];
            if (v < v0 || (v == v0 && ii < i0)) { v0 = v; i0 = ii; }
        }
        pmin[(size_t)(m0 + t) * NCB + bx] = v0;
        pidx[(size_t)(m0 + t) * NCB + bx] = i0;
    }
}

// ---------------- K2: per-token argmin over 20 partials + gather x_q, STE, loss partials ----------------
__global__ __launch_bounds__(256) void gather_kernel(const float* __restrict__ x,
                                                     const float* __restrict__ emb,
                                                     const int* __restrict__ split,
                                                     float* __restrict__ out,
                                                     const float* __restrict__ pmin,
                                                     const int* __restrict__ pidx,
                                                     float* __restrict__ wsLoss) {
    __shared__ float ls[3];
    int t = threadIdx.x, wid = t >> 6, ln = t & 63;
    if (t < 3) ls[t] = 0.f;
    __syncthreads();
    int tok = blockIdx.x * 4 + wid;

    // wave-wide argmin over this token's NCB partials (lanes >= NCB carry sentinels)
    float best = 3.4e38f;
    int bi = 0x7fffffff;
    if (ln < NCB) {
        best = pmin[(size_t)tok * NCB + ln];
        bi   = pidx[(size_t)tok * NCB + ln];
    }
#pragma unroll
    for (int sh = 32; sh; sh >>= 1) {
        float ov = __shfl_xor(best, sh, 64);
        int   oi = __shfl_xor(bi, sh, 64);
        if (ov < best || (ov == best && oi < bi)) { best = ov; bi = oi; }
    }
    if (ln == 0) out[IDX_OFF + tok] = (float)bi;
    int idx = bi;

    f32x4 e  = ((const f32x4*)(emb + (size_t)idx * E_DIM))[ln];
    f32x4 xv = ((const f32x4*)(x + (size_t)tok * E_DIM))[ln];
    f32x4 q;
    float s = 0.f;
#pragma unroll
    for (int c = 0; c < 4; ++c) {
        float d = e[c] - xv[c];
        q[c] = xv[c] + d;               // straight-through: x + (x_q - x)
        s = fmaf(d, d, s);
    }
    ((f32x4*)(out + (size_t)tok * E_DIM))[ln] = q;
#pragma unroll
    for (int sh = 32; sh; sh >>= 1) s += __shfl_xor(s, sh, 64);
    if (ln == 0) {
        int mod = (tok >= split[1]) + (tok >= split[2]);
        atomicAdd(&ls[mod], s);
    }
    __syncthreads();
    if (t < 3) wsLoss[blockIdx.x * 3 + t] = ls[t];
}

// ---------------- K3: final loss reduction ----------------
__global__ __launch_bounds__(256) void loss_kernel(const float* __restrict__ wsLoss,
                                                   const int* __restrict__ split,
                                                   float* __restrict__ out, int nblk) {
    __shared__ float red[256];
    float s[3] = {0.f, 0.f, 0.f};
    for (int b = threadIdx.x; b < nblk; b += 256) {
        s[0] += wsLoss[b * 3 + 0];
        s[1] += wsLoss[b * 3 + 1];
        s[2] += wsLoss[b * 3 + 2];
    }
    for (int m = 0; m < 3; ++m) {
        red[threadIdx.x] = s[m];
        __syncthreads();
        for (int st = 128; st; st >>= 1) {
            if (threadIdx.x < st) red[threadIdx.x] += red[threadIdx.x + st];
            __syncthreads();
        }
        if (threadIdx.x == 0) {
            float cnt = (float)(split[m + 1] - split[m]) * (float)E_DIM;
            float a = red[0] / cnt;
            out[QL_OFF + m] = a + 0.25f * a;   // code + beta*commit (numerically equal)
        }
        __syncthreads();
    }
}

extern "C" void kernel_launch(void* const* d_in, const int* in_sizes, int n_in,
                              void* d_out, int out_size, void* d_ws, size_t ws_size,
                              hipStream_t stream) {
    const float* x   = (const float*)d_in[0];
    const float* emb = (const float*)d_in[1];
    const int* split = (const int*)d_in[2];
    float* out = (float*)d_out;

    float* xx     = (float*)d_ws;                          // 16384 f32
    float* ee     = xx + N_TOK;                            // 5120 f32
    float* wsLoss = ee + N_CODE;                           // 4096*3 f32
    float* pmin   = wsLoss + 4096 * 3;                     // 16384*20 f32
    int*   pidx   = (int*)(pmin + (size_t)N_TOK * NCB);    // 16384*20 i32
    short* xhi    = (short*)(pidx + (size_t)N_TOK * NCB);
    short* xlo    = xhi + (size_t)N_TOK * E_DIM;
    short* ehi    = xlo + (size_t)N_TOK * E_DIM;
    short* elo    = ehi + (size_t)N_CODE * E_DIM;
    int nblkGather = N_TOK / 4;            // 4096

    convert_kernel<<<dim3((N_TOK + N_CODE) / 4), dim3(256), 0, stream>>>(x, emb, xx, ee, xhi, xlo, ehi, elo);
    gemm_kernel<<<dim3(NCB, N_TOK / BM), dim3(512), 0, stream>>>(xhi, xlo, ehi, elo, split, xx, ee, out, pmin, pidx);
    gather_kernel<<<dim3(nblkGather), dim3(256), 0, stream>>>(x, emb, split, out, pmin, pidx, wsLoss);
    loss_kernel<<<dim3(1), dim3(256), 0, stream>>>(wsLoss, split, out, nblkGather);
}

// Round 2
// 478.694 us; speedup vs baseline: 1.0415x; 1.0415x over previous
//
#include <hip/hip_runtime.h>
#include <stdint.h>

#define N_TOK    16384
#define E_DIM    256
#define N_CODE   5120
#define N_SHARED 2048
#define BIGF     1e7f

#define BM  256
#define BN  256
#define BK  32
#define NCB (N_CODE / BN)           // 20 column blocks
#define NKT (E_DIM / BK)            // 8 K-tiles
#define CHUNK (BM * BK)             // 8192 shorts = 16 KB per stream per K-tile

#define IDX_OFF ((size_t)N_TOK * E_DIM)                    // 4194304
#define D_OFF   (IDX_OFF + N_TOK)                          // 4210688
#define QL_OFF  (D_OFF + (size_t)N_TOK * N_CODE)           // 88096768

typedef float f32x4 __attribute__((ext_vector_type(4)));
typedef short bf16x8 __attribute__((ext_vector_type(8)));
typedef short s16x4 __attribute__((ext_vector_type(4)));

typedef __attribute__((address_space(1))) const unsigned int g_u32;
typedef __attribute__((address_space(3))) unsigned int lds_u32;

#define VMW(n) asm volatile("s_waitcnt vmcnt(" #n ")" ::: "memory")

__device__ __forceinline__ unsigned short bf16_rn(float f) {
    unsigned u = __float_as_uint(f);
    u += 0x7FFF + ((u >> 16) & 1);          // round-to-nearest-even
    return (unsigned short)(u >> 16);
}
__device__ __forceinline__ float bf16_to_f(unsigned short h) {
    return __uint_as_float(((unsigned)h) << 16);
}

// ---------------- K0: convert to hi/lo bf16 (fragment-swizzled, 256-row tiles) + row norms ----------------
// layout: [tile(256rows)][kt(8)][quad(4)][row(256)][8] -> linear global_load_lds staging
__global__ __launch_bounds__(256) void convert_kernel(const float* __restrict__ x,
                                                      const float* __restrict__ emb,
                                                      float* __restrict__ xx,
                                                      float* __restrict__ ee,
                                                      short* __restrict__ xhi, short* __restrict__ xlo,
                                                      short* __restrict__ ehi, short* __restrict__ elo) {
    int wid = threadIdx.x >> 6, ln = threadIdx.x & 63;
    int row = blockIdx.x * 4 + wid;             // 0 .. 21503
    const float* src; float* nrm; short *hiA, *loA; int rl, tb;
    if (row < N_TOK) {
        src = x + (size_t)row * E_DIM; nrm = xx + row;
        tb = row >> 8; rl = row & 255; hiA = xhi; loA = xlo;
    } else {
        int r = row - N_TOK;
        src = emb + (size_t)r * E_DIM; nrm = ee + r;
        tb = r >> 8; rl = r & 255; hiA = ehi; loA = elo;
    }
    f32x4 v = ((const f32x4*)src)[ln];          // k = ln*4 .. ln*4+3
    float s = v[0]*v[0] + v[1]*v[1] + v[2]*v[2] + v[3]*v[3];
    s16x4 h, l;
#pragma unroll
    for (int c = 0; c < 4; ++c) {
        unsigned short hh = bf16_rn(v[c]);
        h[c] = (short)hh;
        l[c] = (short)bf16_rn(v[c] - bf16_to_f(hh));
    }
    int kt = ln >> 3, q = (ln >> 1) & 3, kl4 = (ln & 1) * 4;
    size_t di = ((((size_t)tb * NKT + kt) * 4 + q) * BM + rl) * 8 + kl4;
    *(s16x4*)&hiA[di] = h;
    *(s16x4*)&loA[di] = l;
#pragma unroll
    for (int sh = 32; sh; sh >>= 1) s += __shfl_xor(s, sh, 64);
    if (ln == 0) *nrm = s;
}

// ---------------- K1: distance GEMM (256x256, counted-vmcnt pipeline) + mask + per-block argmin ----------------
// d-stores are NON-TEMPORAL: d is write-only; keeping it out of L2/LLC preserves
// the 44 MB of staged bf16 operands in cache (theory: gemm was HBM-read-bound from
// streaming-write thrash, which is why the pipelined K-loop was neutral).
__global__ __launch_bounds__(512, 2) void gemm_kernel(const short* __restrict__ xhi,
                                                      const short* __restrict__ xlo,
                                                      const short* __restrict__ ehi,
                                                      const short* __restrict__ elo,
                                                      const int* __restrict__ split,
                                                      const float* __restrict__ xx,
                                                      const float* __restrict__ ee,
                                                      float* __restrict__ out,
                                                      float* __restrict__ pmin,
                                                      int*   __restrict__ pidx) {
    __shared__ short Ah[2][CHUNK], Bh[2][CHUNK];   // unit U0 (hi), double-buffered
    __shared__ short Al[2][CHUNK], Bl[2][CHUNK];   // unit U1 (lo), double-buffered
    __shared__ float xxs[BM];
    __shared__ float ees[BN];
    __shared__ float redv[4][BM];
    __shared__ int   redi[4][BM];

    const int bx = blockIdx.x;      // code block 0..19
    const int by = blockIdx.y;      // token block 0..63
    const int m0 = by * BM, n0 = bx * BN;
    const int t = threadIdx.x;

    const int s1 = split[1], s2v = split[2];
    const int tmFirst = (m0 >= s1) + (m0 >= s2v);
    const int tmLast  = ((m0 + BM - 1) >= s1) + ((m0 + BM - 1) >= s2v);
    const bool rowUni = (tmFirst == tmLast);
    const int cmod = (n0 < N_SHARED) ? -1 : ((n0 - N_SHARED) >> 10);

    float* dOut = out + D_OFF;

    // fully-masked block: pure BIG fill (nt, lane-contiguous), no GEMM
    if (cmod >= 0 && rowUni && cmod != tmFirst) {
        f32x4 big = {BIGF, BIGF, BIGF, BIGF};
#pragma unroll
        for (int u = 0; u < 32; ++u) {
            int idx = u * 512 + t;              // 0 .. 16383 f32x4 positions
            int row = idx >> 6, col4 = idx & 63;
            __builtin_nontemporal_store(big,
                (f32x4*)(dOut + (size_t)(m0 + row) * N_CODE + n0) + col4);
        }
        if (t < BM) {
            pmin[(size_t)(m0 + t) * NCB + bx] = BIGF;
            pidx[(size_t)(m0 + t) * NCB + bx] = n0;
        }
        return;
    }

    const bool allAllowed = (cmod < 0) || (rowUni && cmod == tmFirst);

    if (t < BM) xxs[t] = xx[m0 + t];
    else        ees[t - BM] = ee[n0 + (t - BM)];
    __syncthreads();                // drain xx/ee loads (vmcnt 0) so manual counts see staging only

    f32x4 acc[8][4] = {};

    const int wid = t >> 6, lane = t & 63;
    const int quad = lane >> 4, ln16 = lane & 15;
    const int wr = (wid >> 2) * 128, wc = (wid & 3) * 64;
    const int qb = quad * BM;

    const short* aHiG = xhi + (size_t)by * NKT * CHUNK;
    const short* aLoG = xlo + (size_t)by * NKT * CHUNK;
    const short* bHiG = ehi + (size_t)bx * NKT * CHUNK;
    const short* bLoG = elo + (size_t)bx * NKT * CHUNK;
    const int tOff = t * 8;                     // shorts (16 B per thread per round)

    auto stageU0 = [&](int kt, int b) {         // 4 glds: Ah, Bh
        const size_t co = (size_t)kt * CHUNK;
#pragma unroll
        for (int p = 0; p < 2; ++p) {
            int o = p * 4096 + tOff;
            __builtin_amdgcn_global_load_lds((g_u32*)(aHiG + co + o), (lds_u32*)&Ah[b][o], 16, 0, 0);
            __builtin_amdgcn_global_load_lds((g_u32*)(bHiG + co + o), (lds_u32*)&Bh[b][o], 16, 0, 0);
        }
    };
    auto stageU1 = [&](int kt, int b) {         // 4 glds: Al, Bl
        const size_t co = (size_t)kt * CHUNK;
#pragma unroll
        for (int p = 0; p < 2; ++p) {
            int o = p * 4096 + tOff;
            __builtin_amdgcn_global_load_lds((g_u32*)(aLoG + co + o), (lds_u32*)&Al[b][o], 16, 0, 0);
            __builtin_amdgcn_global_load_lds((g_u32*)(bLoG + co + o), (lds_u32*)&Bl[b][o], 16, 0, 0);
        }
    };

    // prologue: U0(0), U1(0), U0(1) in flight (12 vmem ops)
    stageU0(0, 0); stageU1(0, 0); stageU0(1, 1);
    int cur = 0;

    // Per tile: phase A needs U0(t) -> wait leaving {U1(t), U0(t+1)} = 8 in flight.
    //           phase B needs U1(t) -> wait leaving {U0(t+1), U1(t+1)} = 8 in flight.
    // vmcnt hits 0 only in the final tile.
#define TILE(VA, VB, DOU1, DOU2, KT)                                                         \
    {                                                                                        \
        VMW(VA);                                                                             \
        __builtin_amdgcn_s_barrier();                                                        \
        if (DOU1) stageU1((KT) + 1, cur ^ 1);                                                \
        bf16x8 ah[8], bh[4];                                                                 \
        _Pragma("unroll") for (int i = 0; i < 8; ++i)                                        \
            ah[i] = *(const bf16x8*)&Ah[cur][(qb + wr + i * 16 + ln16) * 8];                 \
        _Pragma("unroll") for (int j = 0; j < 4; ++j)                                        \
            bh[j] = *(const bf16x8*)&Bh[cur][(qb + wc + j * 16 + ln16) * 8];                 \
        __builtin_amdgcn_s_setprio(1);                                                       \
        _Pragma("unroll") for (int i = 0; i < 8; ++i)                                        \
            _Pragma("unroll") for (int j = 0; j < 4; ++j)                                    \
                acc[i][j] = __builtin_amdgcn_mfma_f32_16x16x32_bf16(ah[i], bh[j], acc[i][j], 0, 0, 0); \
        __builtin_amdgcn_s_setprio(0);                                                       \
        VMW(VB);                                                                             \
        __builtin_amdgcn_s_barrier();                                                        \
        if (DOU2) stageU0((KT) + 2, cur);                                                    \
        bf16x8 bl[4];                                                                        \
        _Pragma("unroll") for (int j = 0; j < 4; ++j)                                        \
            bl[j] = *(const bf16x8*)&Bl[cur][(qb + wc + j * 16 + ln16) * 8];                 \
        __builtin_amdgcn_s_setprio(1);                                                       \
        _Pragma("unroll") for (int i = 0; i < 8; ++i)                                        \
            _Pragma("unroll") for (int j = 0; j < 4; ++j)                                    \
                acc[i][j] = __builtin_amdgcn_mfma_f32_16x16x32_bf16(ah[i], bl[j], acc[i][j], 0, 0, 0); \
        __builtin_amdgcn_s_setprio(0);                                                       \
        bf16x8 al[8];                                                                        \
        _Pragma("unroll") for (int i = 0; i < 8; ++i)                                        \
            al[i] = *(const bf16x8*)&Al[cur][(qb + wr + i * 16 + ln16) * 8];                 \
        __builtin_amdgcn_s_setprio(1);                                                       \
        _Pragma("unroll") for (int i = 0; i < 8; ++i)                                        \
            _Pragma("unroll") for (int j = 0; j < 4; ++j)                                    \
                acc[i][j] = __builtin_amdgcn_mfma_f32_16x16x32_bf16(al[i], bh[j], acc[i][j], 0, 0, 0); \
        __builtin_amdgcn_s_setprio(0);                                                       \
        cur ^= 1;                                                                            \
    }

    for (int kt = 0; kt < NKT - 2; ++kt)
        TILE(8, 8, true, true, kt);
    TILE(8, 8, true, false, NKT - 2);
    TILE(4, 0, false, false, NKT - 1);
#undef TILE

    // epilogue: d = xx + ee - 2*dot, mask, nt-store, row-argmin over this block
#pragma unroll
    for (int i = 0; i < 8; ++i) {
#pragma unroll
        for (int r = 0; r < 4; ++r) {
            int lm = wr + i * 16 + quad * 4 + r;     // local row (C/D: row = quad*4+reg)
            int gm = m0 + lm;
            float xv = xxs[lm];
            int tmod = (gm >= s1) + (gm >= s2v);
            float best = 3.4e38f;
            int bidx = n0;
#pragma unroll
            for (int j = 0; j < 4; ++j) {
                int lnn = wc + j * 16 + ln16;        // local col (C/D: col = lane&15)
                int gn = n0 + lnn;
                float dv = fmaf(-2.f, acc[i][j][r], xv + ees[lnn]);
                if (!allAllowed) {
                    bool ok = (gn < N_SHARED) || (((gn - N_SHARED) >> 10) == tmod);
                    if (!ok) dv = BIGF;
                }
                __builtin_nontemporal_store(dv, &dOut[(size_t)gm * N_CODE + gn]);
                if (dv < best) { best = dv; bidx = gn; }   // j ascending: ties keep lowest gn
            }
#pragma unroll
            for (int s = 1; s < 16; s <<= 1) {
                float ov = __shfl_xor(best, s, 64);
                int   oi = __shfl_xor(bidx, s, 64);
                if (ov < best || (ov == best && oi < bidx)) { best = ov; bidx = oi; }
            }
            if (ln16 == 0) { redv[wid & 3][lm] = best; redi[wid & 3][lm] = bidx; }
        }
    }
    __syncthreads();
    if (t < BM) {
        float v0 = redv[0][t]; int i0 = redi[0][t];
#pragma unroll
        for (int w = 1; w < 4; ++w) {
            float v = redv[w][t]; int ii = redi[w][t];
            if (v < v0 || (v == v0 && ii < i0)) { v0 = v; i0 = ii; }
        }
        pmin[(size_t)(m0 + t) * NCB + bx] = v0;
        pidx[(size_t)(m0 + t) * NCB + bx] = i0;
    }
}

// ---------------- K2: per-token argmin over 20 partials + gather x_q, STE, loss partials ----------------
__global__ __launch_bounds__(256) void gather_kernel(const float* __restrict__ x,
                                                     const float* __restrict__ emb,
                                                     const int* __restrict__ split,
                                                     float* __restrict__ out,
                                                     const float* __restrict__ pmin,
                                                     const int* __restrict__ pidx,
                                                     float* __restrict__ wsLoss) {
    __shared__ float ls[3];
    int t = threadIdx.x, wid = t >> 6, ln = t & 63;
    if (t < 3) ls[t] = 0.f;
    __syncthreads();
    int tok = blockIdx.x * 4 + wid;

    // wave-wide argmin over this token's NCB partials (lanes >= NCB carry sentinels)
    float best = 3.4e38f;
    int bi = 0x7fffffff;
    if (ln < NCB) {
        best = pmin[(size_t)tok * NCB + ln];
        bi   = pidx[(size_t)tok * NCB + ln];
    }
#pragma unroll
    for (int sh = 32; sh; sh >>= 1) {
        float ov = __shfl_xor(best, sh, 64);
        int   oi = __shfl_xor(bi, sh, 64);
        if (ov < best || (ov == best && oi < bi)) { best = ov; bi = oi; }
    }
    if (ln == 0) out[IDX_OFF + tok] = (float)bi;
    int idx = bi;

    f32x4 e  = ((const f32x4*)(emb + (size_t)idx * E_DIM))[ln];
    f32x4 xv = ((const f32x4*)(x + (size_t)tok * E_DIM))[ln];
    f32x4 q;
    float s = 0.f;
#pragma unroll
    for (int c = 0; c < 4; ++c) {
        float d = e[c] - xv[c];
        q[c] = xv[c] + d;               // straight-through: x + (x_q - x)
        s = fmaf(d, d, s);
    }
    __builtin_nontemporal_store(q, (f32x4*)(out + (size_t)tok * E_DIM) + ln);
#pragma unroll
    for (int sh = 32; sh; sh >>= 1) s += __shfl_xor(s, sh, 64);
    if (ln == 0) {
        int mod = (tok >= split[1]) + (tok >= split[2]);
        atomicAdd(&ls[mod], s);
    }
    __syncthreads();
    if (t < 3) wsLoss[blockIdx.x * 3 + t] = ls[t];
}

// ---------------- K3: final loss reduction ----------------
__global__ __launch_bounds__(256) void loss_kernel(const float* __restrict__ wsLoss,
                                                   const int* __restrict__ split,
                                                   float* __restrict__ out, int nblk) {
    __shared__ float red[256];
    float s[3] = {0.f, 0.f, 0.f};
    for (int b = threadIdx.x; b < nblk; b += 256) {
        s[0] += wsLoss[b * 3 + 0];
        s[1] += wsLoss[b * 3 + 1];
        s[2] += wsLoss[b * 3 + 2];
    }
    for (int m = 0; m < 3; ++m) {
        red[threadIdx.x] = s[m];
        __syncthreads();
        for (int st = 128; st; st >>= 1) {
            if (threadIdx.x < st) red[threadIdx.x] += red[threadIdx.x + st];
            __syncthreads();
        }
        if (threadIdx.x == 0) {
            float cnt = (float)(split[m + 1] - split[m]) * (float)E_DIM;
            float a = red[0] / cnt;
            out[QL_OFF + m] = a + 0.25f * a;   // code + beta*commit (numerically equal)
        }
        __syncthreads();
    }
}

extern "C" void kernel_launch(void* const* d_in, const int* in_sizes, int n_in,
                              void* d_out, int out_size, void* d_ws, size_t ws_size,
                              hipStream_t stream) {
    const float* x   = (const float*)d_in[0];
    const float* emb = (const float*)d_in[1];
    const int* split = (const int*)d_in[2];
    float* out = (float*)d_out;

    float* xx     = (float*)d_ws;                          // 16384 f32
    float* ee     = xx + N_TOK;                            // 5120 f32
    float* wsLoss = ee + N_CODE;                           // 4096*3 f32
    float* pmin   = wsLoss + 4096 * 3;                     // 16384*20 f32
    int*   pidx   = (int*)(pmin + (size_t)N_TOK * NCB);    // 16384*20 i32
    short* xhi    = (short*)(pidx + (size_t)N_TOK * NCB);
    short* xlo    = xhi + (size_t)N_TOK * E_DIM;
    short* ehi    = xlo + (size_t)N_TOK * E_DIM;
    short* elo    = ehi + (size_t)N_CODE * E_DIM;
    int nblkGather = N_TOK / 4;            // 4096

    convert_kernel<<<dim3((N_TOK + N_CODE) / 4), dim3(256), 0, stream>>>(x, emb, xx, ee, xhi, xlo, ehi, elo);
    gemm_kernel<<<dim3(NCB, N_TOK / BM), dim3(512), 0, stream>>>(xhi, xlo, ehi, elo, split, xx, ee, out, pmin, pidx);
    gather_kernel<<<dim3(nblkGather), dim3(256), 0, stream>>>(x, emb, split, out, pmin, pidx, wsLoss);
    loss_kernel<<<dim3(1), dim3(256), 0, stream>>>(wsLoss, split, out, nblkGather);
}

// Round 3
// 449.830 us; speedup vs baseline: 1.1083x; 1.0642x over previous
//
#include <hip/hip_runtime.h>
#include <stdint.h>

#define N_TOK    16384
#define E_DIM    256
#define N_CODE   5120
#define N_SHARED 2048
#define BIGF     1e7f

#define BM  128
#define BN  128
#define BK  32
#define NCB (N_CODE / BN)           // 40 column blocks
#define NKT (E_DIM / BK)            // 8 K-tiles
#define CHUNK (BM * BK)             // 4096 shorts = 8 KB per stream per K-tile
#define NBLK (NCB * (N_TOK / BM))   // 5120 blocks, %8 == 0 -> simple XCD swizzle bijective

#define IDX_OFF ((size_t)N_TOK * E_DIM)                    // 4194304
#define D_OFF   (IDX_OFF + N_TOK)                          // 4210688
#define QL_OFF  (D_OFF + (size_t)N_TOK * N_CODE)           // 88096768

typedef float f32x4 __attribute__((ext_vector_type(4)));
typedef short bf16x8 __attribute__((ext_vector_type(8)));
typedef short s16x4 __attribute__((ext_vector_type(4)));

typedef __attribute__((address_space(1))) const unsigned int g_u32;
typedef __attribute__((address_space(3))) unsigned int lds_u32;

#define VMW(n) asm volatile("s_waitcnt vmcnt(" #n ")" ::: "memory")

__device__ __forceinline__ unsigned short bf16_rn(float f) {
    unsigned u = __float_as_uint(f);
    u += 0x7FFF + ((u >> 16) & 1);          // round-to-nearest-even
    return (unsigned short)(u >> 16);
}
__device__ __forceinline__ float bf16_to_f(unsigned short h) {
    return __uint_as_float(((unsigned)h) << 16);
}

// ---------------- K0: convert to hi/lo bf16 (fragment-swizzled, 128-row tiles) + row norms ----------------
// layout: [tile(128rows)][kt(8)][quad(4)][row(128)][8] -> linear global_load_lds staging
__global__ __launch_bounds__(256) void convert_kernel(const float* __restrict__ x,
                                                      const float* __restrict__ emb,
                                                      float* __restrict__ xx,
                                                      float* __restrict__ ee,
                                                      short* __restrict__ xhi, short* __restrict__ xlo,
                                                      short* __restrict__ ehi, short* __restrict__ elo) {
    int wid = threadIdx.x >> 6, ln = threadIdx.x & 63;
    int row = blockIdx.x * 4 + wid;             // 0 .. 21503
    const float* src; float* nrm; short *hiA, *loA; int rl, tb;
    if (row < N_TOK) {
        src = x + (size_t)row * E_DIM; nrm = xx + row;
        tb = row >> 7; rl = row & 127; hiA = xhi; loA = xlo;
    } else {
        int r = row - N_TOK;
        src = emb + (size_t)r * E_DIM; nrm = ee + r;
        tb = r >> 7; rl = r & 127; hiA = ehi; loA = elo;
    }
    f32x4 v = ((const f32x4*)src)[ln];          // k = ln*4 .. ln*4+3
    float s = v[0]*v[0] + v[1]*v[1] + v[2]*v[2] + v[3]*v[3];
    s16x4 h, l;
#pragma unroll
    for (int c = 0; c < 4; ++c) {
        unsigned short hh = bf16_rn(v[c]);
        h[c] = (short)hh;
        l[c] = (short)bf16_rn(v[c] - bf16_to_f(hh));
    }
    int kt = ln >> 3, q = (ln >> 1) & 3, kl4 = (ln & 1) * 4;
    size_t di = ((((size_t)tb * NKT + kt) * 4 + q) * BM + rl) * 8 + kl4;
    *(s16x4*)&hiA[di] = h;
    *(s16x4*)&loA[di] = l;
#pragma unroll
    for (int sh = 32; sh; sh >>= 1) s += __shfl_xor(s, sh, 64);
    if (ln == 0) *nrm = s;
}

// ---------------- K1: distance GEMM (128x128, 2 blocks/CU, counted-vmcnt) + mask + per-block argmin ----------------
// 67 KB LDS -> 2 blocks/CU so one block's NT d-store epilogue overlaps the other's K-loop
// (round-2 lesson: at 1 block/CU the 256KB store burst serialized with compute).
// XCD swizzle: 40 consecutive blocks per XCD share one A-panel (L2-resident reads).
__global__ __launch_bounds__(256, 2) void gemm_kernel(const short* __restrict__ xhi,
                                                      const short* __restrict__ xlo,
                                                      const short* __restrict__ ehi,
                                                      const short* __restrict__ elo,
                                                      const int* __restrict__ split,
                                                      const float* __restrict__ xx,
                                                      const float* __restrict__ ee,
                                                      float* __restrict__ out,
                                                      float* __restrict__ pmin,
                                                      int*   __restrict__ pidx) {
    __shared__ short Ah[2][CHUNK], Bh[2][CHUNK];   // unit U0 (hi), double-buffered
    __shared__ short Al[2][CHUNK], Bl[2][CHUNK];   // unit U1 (lo), double-buffered
    __shared__ float xxs[BM];
    __shared__ float ees[BN];
    __shared__ float redv[2][BM];
    __shared__ int   redi[2][BM];

    // T1 XCD-aware swizzle (NBLK % 8 == 0 -> bijective): XCD k owns s in [k*640,(k+1)*640)
    const int lin = blockIdx.y * NCB + blockIdx.x;
    const int s_  = (lin & 7) * (NBLK / 8) + (lin >> 3);
    const int bx = s_ % NCB;        // code block 0..39
    const int by = s_ / NCB;        // token block 0..127
    const int m0 = by * BM, n0 = bx * BN;
    const int t = threadIdx.x;

    const int s1 = split[1], s2v = split[2];
    const int tmFirst = (m0 >= s1) + (m0 >= s2v);     // 128-row blocks are modality-uniform
    const int cmod = (n0 < N_SHARED) ? -1 : ((n0 - N_SHARED) >> 10);

    float* dOut = out + D_OFF;

    // fully-masked block: pure BIG fill (nt, lane-contiguous), no GEMM
    if (cmod >= 0 && cmod != tmFirst) {
        f32x4 big = {BIGF, BIGF, BIGF, BIGF};
#pragma unroll
        for (int u = 0; u < 16; ++u) {
            int idx = u * 256 + t;              // 0 .. 4095 f32x4 positions
            int row = idx >> 5, col4 = idx & 31;
            __builtin_nontemporal_store(big,
                (f32x4*)(dOut + (size_t)(m0 + row) * N_CODE + n0) + col4);
        }
        if (t < BM) {
            pmin[(size_t)(m0 + t) * NCB + bx] = BIGF;
            pidx[(size_t)(m0 + t) * NCB + bx] = n0;
        }
        return;
    }

    const bool allAllowed = (cmod < 0);

    if (t < BM) xxs[t] = xx[m0 + t];
    else        ees[t - BM] = ee[n0 + (t - BM)];
    __syncthreads();                // drain xx/ee loads so manual vmcnt counts see staging only

    f32x4 acc[4][4] = {};

    const int wid = t >> 6, lane = t & 63;
    const int quad = lane >> 4, ln16 = lane & 15;
    const int wr = (wid >> 1) * 64, wc = (wid & 1) * 64;
    const int qb = quad * BM;

    const short* aHiG = xhi + (size_t)by * NKT * CHUNK;
    const short* aLoG = xlo + (size_t)by * NKT * CHUNK;
    const short* bHiG = ehi + (size_t)bx * NKT * CHUNK;
    const short* bLoG = elo + (size_t)bx * NKT * CHUNK;
    const int tOff = t * 8;                     // shorts (16 B per thread per round)

    auto stageU0 = [&](int kt, int b) {         // 4 glds: Ah, Bh
        const size_t co = (size_t)kt * CHUNK;
#pragma unroll
        for (int p = 0; p < 2; ++p) {
            int o = p * 2048 + tOff;
            __builtin_amdgcn_global_load_lds((g_u32*)(aHiG + co + o), (lds_u32*)&Ah[b][o], 16, 0, 0);
            __builtin_amdgcn_global_load_lds((g_u32*)(bHiG + co + o), (lds_u32*)&Bh[b][o], 16, 0, 0);
        }
    };
    auto stageU1 = [&](int kt, int b) {         // 4 glds: Al, Bl
        const size_t co = (size_t)kt * CHUNK;
#pragma unroll
        for (int p = 0; p < 2; ++p) {
            int o = p * 2048 + tOff;
            __builtin_amdgcn_global_load_lds((g_u32*)(aLoG + co + o), (lds_u32*)&Al[b][o], 16, 0, 0);
            __builtin_amdgcn_global_load_lds((g_u32*)(bLoG + co + o), (lds_u32*)&Bl[b][o], 16, 0, 0);
        }
    };

    // prologue: U0(0), U1(0), U0(1) in flight (12 vmem ops)
    stageU0(0, 0); stageU1(0, 0); stageU0(1, 1);
    int cur = 0;

    // Per tile: phase A needs U0(t) -> wait leaving {U1(t), U0(t+1)} = 8 in flight.
    //           phase B/C need U1(t) -> wait leaving {U0(t+1), U1(t+1)} = 8 in flight.
    // vmcnt hits 0 only in the final tile.
#define TILE(VA, VB, DOU1, DOU2, KT)                                                         \
    {                                                                                        \
        VMW(VA);                                                                             \
        __builtin_amdgcn_s_barrier();                                                        \
        if (DOU1) stageU1((KT) + 1, cur ^ 1);                                                \
        bf16x8 ah[4], bh[4];                                                                 \
        _Pragma("unroll") for (int i = 0; i < 4; ++i)                                        \
            ah[i] = *(const bf16x8*)&Ah[cur][(qb + wr + i * 16 + ln16) * 8];                 \
        _Pragma("unroll") for (int j = 0; j < 4; ++j)                                        \
            bh[j] = *(const bf16x8*)&Bh[cur][(qb + wc + j * 16 + ln16) * 8];                 \
        __builtin_amdgcn_s_setprio(1);                                                       \
        _Pragma("unroll") for (int i = 0; i < 4; ++i)                                        \
            _Pragma("unroll") for (int j = 0; j < 4; ++j)                                    \
                acc[i][j] = __builtin_amdgcn_mfma_f32_16x16x32_bf16(ah[i], bh[j], acc[i][j], 0, 0, 0); \
        __builtin_amdgcn_s_setprio(0);                                                       \
        VMW(VB);                                                                             \
        __builtin_amdgcn_s_barrier();                                                        \
        if (DOU2) stageU0((KT) + 2, cur);                                                    \
        bf16x8 bl[4];                                                                        \
        _Pragma("unroll") for (int j = 0; j < 4; ++j)                                        \
            bl[j] = *(const bf16x8*)&Bl[cur][(qb + wc + j * 16 + ln16) * 8];                 \
        __builtin_amdgcn_s_setprio(1);                                                       \
        _Pragma("unroll") for (int i = 0; i < 4; ++i)                                        \
            _Pragma("unroll") for (int j = 0; j < 4; ++j)                                    \
                acc[i][j] = __builtin_amdgcn_mfma_f32_16x16x32_bf16(ah[i], bl[j], acc[i][j], 0, 0, 0); \
        __builtin_amdgcn_s_setprio(0);                                                       \
        bf16x8 al[4];                                                                        \
        _Pragma("unroll") for (int i = 0; i < 4; ++i)                                        \
            al[i] = *(const bf16x8*)&Al[cur][(qb + wr + i * 16 + ln16) * 8];                 \
        __builtin_amdgcn_s_setprio(1);                                                       \
        _Pragma("unroll") for (int i = 0; i < 4; ++i)                                        \
            _Pragma("unroll") for (int j = 0; j < 4; ++j)                                    \
                acc[i][j] = __builtin_amdgcn_mfma_f32_16x16x32_bf16(al[i], bh[j], acc[i][j], 0, 0, 0); \
        __builtin_amdgcn_s_setprio(0);                                                       \
        cur ^= 1;                                                                            \
    }

    for (int kt = 0; kt < NKT - 2; ++kt)
        TILE(8, 8, true, true, kt);
    TILE(8, 8, true, false, NKT - 2);
    TILE(4, 0, false, false, NKT - 1);
#undef TILE

    // epilogue: d = xx + ee - 2*dot, mask, nt-store, row-argmin over this block
#pragma unroll
    for (int i = 0; i < 4; ++i) {
#pragma unroll
        for (int r = 0; r < 4; ++r) {
            int lm = wr + i * 16 + quad * 4 + r;     // local row (C/D: row = quad*4+reg)
            int gm = m0 + lm;
            float xv = xxs[lm];
            int tmod = (gm >= s1) + (gm >= s2v);
            float best = 3.4e38f;
            int bidx = n0;
#pragma unroll
            for (int j = 0; j < 4; ++j) {
                int lnn = wc + j * 16 + ln16;        // local col (C/D: col = lane&15)
                int gn = n0 + lnn;
                float dv = fmaf(-2.f, acc[i][j][r], xv + ees[lnn]);
                if (!allAllowed) {
                    bool ok = (gn < N_SHARED) || (((gn - N_SHARED) >> 10) == tmod);
                    if (!ok) dv = BIGF;
                }
                __builtin_nontemporal_store(dv, &dOut[(size_t)gm * N_CODE + gn]);
                if (dv < best) { best = dv; bidx = gn; }   // j ascending: ties keep lowest gn
            }
#pragma unroll
            for (int s = 1; s < 16; s <<= 1) {
                float ov = __shfl_xor(best, s, 64);
                int   oi = __shfl_xor(bidx, s, 64);
                if (ov < best || (ov == best && oi < bidx)) { best = ov; bidx = oi; }
            }
            if (ln16 == 0) { redv[wid & 1][lm] = best; redi[wid & 1][lm] = bidx; }
        }
    }
    __syncthreads();
    if (t < BM) {
        float v0 = redv[0][t]; int i0 = redi[0][t];
        float v1 = redv[1][t]; int i1 = redi[1][t];
        if (v1 < v0 || (v1 == v0 && i1 < i0)) { v0 = v1; i0 = i1; }
        pmin[(size_t)(m0 + t) * NCB + bx] = v0;
        pidx[(size_t)(m0 + t) * NCB + bx] = i0;
    }
}

// ---------------- K2: per-token argmin over 40 partials + gather x_q, STE, loss partials ----------------
__global__ __launch_bounds__(256) void gather_kernel(const float* __restrict__ x,
                                                     const float* __restrict__ emb,
                                                     const int* __restrict__ split,
                                                     float* __restrict__ out,
                                                     const float* __restrict__ pmin,
                                                     const int* __restrict__ pidx,
                                                     float* __restrict__ wsLoss) {
    __shared__ float ls[3];
    int t = threadIdx.x, wid = t >> 6, ln = t & 63;
    if (t < 3) ls[t] = 0.f;
    __syncthreads();
    int tok = blockIdx.x * 4 + wid;

    // wave-wide argmin over this token's NCB partials (lanes >= NCB carry sentinels)
    float best = 3.4e38f;
    int bi = 0x7fffffff;
    if (ln < NCB) {
        best = pmin[(size_t)tok * NCB + ln];
        bi   = pidx[(size_t)tok * NCB + ln];
    }
#pragma unroll
    for (int sh = 32; sh; sh >>= 1) {
        float ov = __shfl_xor(best, sh, 64);
        int   oi = __shfl_xor(bi, sh, 64);
        if (ov < best || (ov == best && oi < bi)) { best = ov; bi = oi; }
    }
    if (ln == 0) out[IDX_OFF + tok] = (float)bi;
    int idx = bi;

    f32x4 e  = ((const f32x4*)(emb + (size_t)idx * E_DIM))[ln];
    f32x4 xv = ((const f32x4*)(x + (size_t)tok * E_DIM))[ln];
    f32x4 q;
    float s = 0.f;
#pragma unroll
    for (int c = 0; c < 4; ++c) {
        float d = e[c] - xv[c];
        q[c] = xv[c] + d;               // straight-through: x + (x_q - x)
        s = fmaf(d, d, s);
    }
    __builtin_nontemporal_store(q, (f32x4*)(out + (size_t)tok * E_DIM) + ln);
#pragma unroll
    for (int sh = 32; sh; sh >>= 1) s += __shfl_xor(s, sh, 64);
    if (ln == 0) {
        int mod = (tok >= split[1]) + (tok >= split[2]);
        atomicAdd(&ls[mod], s);
    }
    __syncthreads();
    if (t < 3) wsLoss[blockIdx.x * 3 + t] = ls[t];
}

// ---------------- K3: final loss reduction ----------------
__global__ __launch_bounds__(256) void loss_kernel(const float* __restrict__ wsLoss,
                                                   const int* __restrict__ split,
                                                   float* __restrict__ out, int nblk) {
    __shared__ float red[256];
    float s[3] = {0.f, 0.f, 0.f};
    for (int b = threadIdx.x; b < nblk; b += 256) {
        s[0] += wsLoss[b * 3 + 0];
        s[1] += wsLoss[b * 3 + 1];
        s[2] += wsLoss[b * 3 + 2];
    }
    for (int m = 0; m < 3; ++m) {
        red[threadIdx.x] = s[m];
        __syncthreads();
        for (int st = 128; st; st >>= 1) {
            if (threadIdx.x < st) red[threadIdx.x] += red[threadIdx.x + st];
            __syncthreads();
        }
        if (threadIdx.x == 0) {
            float cnt = (float)(split[m + 1] - split[m]) * (float)E_DIM;
            float a = red[0] / cnt;
            out[QL_OFF + m] = a + 0.25f * a;   // code + beta*commit (numerically equal)
        }
        __syncthreads();
    }
}

extern "C" void kernel_launch(void* const* d_in, const int* in_sizes, int n_in,
                              void* d_out, int out_size, void* d_ws, size_t ws_size,
                              hipStream_t stream) {
    const float* x   = (const float*)d_in[0];
    const float* emb = (const float*)d_in[1];
    const int* split = (const int*)d_in[2];
    float* out = (float*)d_out;

    float* xx     = (float*)d_ws;                          // 16384 f32
    float* ee     = xx + N_TOK;                            // 5120 f32
    float* wsLoss = ee + N_CODE;                           // 4096*3 f32
    float* pmin   = wsLoss + 4096 * 3;                     // 16384*40 f32
    int*   pidx   = (int*)(pmin + (size_t)N_TOK * NCB);    // 16384*40 i32
    short* xhi    = (short*)(pidx + (size_t)N_TOK * NCB);
    short* xlo    = xhi + (size_t)N_TOK * E_DIM;
    short* ehi    = xlo + (size_t)N_TOK * E_DIM;
    short* elo    = ehi + (size_t)N_CODE * E_DIM;
    int nblkGather = N_TOK / 4;            // 4096

    convert_kernel<<<dim3((N_TOK + N_CODE) / 4), dim3(256), 0, stream>>>(x, emb, xx, ee, xhi, xlo, ehi, elo);
    gemm_kernel<<<dim3(NCB, N_TOK / BM), dim3(256), 0, stream>>>(xhi, xlo, ehi, elo, split, xx, ee, out, pmin, pidx);
    gather_kernel<<<dim3(nblkGather), dim3(256), 0, stream>>>(x, emb, split, out, pmin, pidx, wsLoss);
    loss_kernel<<<dim3(1), dim3(256), 0, stream>>>(wsLoss, split, out, nblkGather);
}

// Round 4
// 427.939 us; speedup vs baseline: 1.1650x; 1.0512x over previous
//
#include <hip/hip_runtime.h>
#include <stdint.h>

#define N_TOK    16384
#define E_DIM    256
#define N_CODE   5120
#define N_SHARED 2048
#define BIGF     1e7f

#define BM  128
#define BN  128
#define BK  32
#define NCB (N_CODE / BN)           // 40 column blocks
#define NKT (E_DIM / BK)            // 8 K-tiles
#define CHUNK (BM * BK)             // 4096 shorts = 8 KB per stream per K-tile
#define NBLK (NCB * (N_TOK / BM))   // 5120 blocks, %8 == 0 -> simple XCD swizzle bijective

#define IDX_OFF ((size_t)N_TOK * E_DIM)                    // 4194304
#define D_OFF   (IDX_OFF + N_TOK)                          // 4210688
#define QL_OFF  (D_OFF + (size_t)N_TOK * N_CODE)           // 88096768

typedef float f32x4 __attribute__((ext_vector_type(4)));
typedef short bf16x8 __attribute__((ext_vector_type(8)));
typedef short s16x4 __attribute__((ext_vector_type(4)));

typedef __attribute__((address_space(1))) const unsigned int g_u32;
typedef __attribute__((address_space(3))) unsigned int lds_u32;

#define VMW(n) asm volatile("s_waitcnt vmcnt(" #n ")" ::: "memory")

__device__ __forceinline__ unsigned short bf16_rn(float f) {
    unsigned u = __float_as_uint(f);
    u += 0x7FFF + ((u >> 16) & 1);          // round-to-nearest-even
    return (unsigned short)(u >> 16);
}
__device__ __forceinline__ float bf16_to_f(unsigned short h) {
    return __uint_as_float(((unsigned)h) << 16);
}

// ---------------- K0: convert to hi/lo bf16 (fragment-swizzled, 128-row tiles) + row norms ----------------
// layout: [tile(128rows)][kt(8)][quad(4)][row(128)][8] -> linear global_load_lds staging
__global__ __launch_bounds__(256) void convert_kernel(const float* __restrict__ x,
                                                      const float* __restrict__ emb,
                                                      float* __restrict__ xx,
                                                      float* __restrict__ ee,
                                                      short* __restrict__ xhi, short* __restrict__ xlo,
                                                      short* __restrict__ ehi, short* __restrict__ elo) {
    int wid = threadIdx.x >> 6, ln = threadIdx.x & 63;
    int row = blockIdx.x * 4 + wid;             // 0 .. 21503
    const float* src; float* nrm; short *hiA, *loA; int rl, tb;
    if (row < N_TOK) {
        src = x + (size_t)row * E_DIM; nrm = xx + row;
        tb = row >> 7; rl = row & 127; hiA = xhi; loA = xlo;
    } else {
        int r = row - N_TOK;
        src = emb + (size_t)r * E_DIM; nrm = ee + r;
        tb = r >> 7; rl = r & 127; hiA = ehi; loA = elo;
    }
    f32x4 v = ((const f32x4*)src)[ln];          // k = ln*4 .. ln*4+3
    float s = v[0]*v[0] + v[1]*v[1] + v[2]*v[2] + v[3]*v[3];
    s16x4 h, l;
#pragma unroll
    for (int c = 0; c < 4; ++c) {
        unsigned short hh = bf16_rn(v[c]);
        h[c] = (short)hh;
        l[c] = (short)bf16_rn(v[c] - bf16_to_f(hh));
    }
    int kt = ln >> 3, q = (ln >> 1) & 3, kl4 = (ln & 1) * 4;
    size_t di = ((((size_t)tb * NKT + kt) * 4 + q) * BM + rl) * 8 + kl4;
    *(s16x4*)&hiA[di] = h;
    *(s16x4*)&loA[di] = l;
#pragma unroll
    for (int sh = 32; sh; sh >>= 1) s += __shfl_xor(s, sh, 64);
    if (ln == 0) *nrm = s;
}

// ---------------- K1: distance GEMM (128x128, 2 blocks/CU, counted-vmcnt) + per-block argmin ----------------
// MFMA operands SWAPPED (mfma(b,a)): C/D regs = 4 consecutive CODES of one token ->
// epilogue stores are f32x4 along the d row (16 x4-stores/thread vs 64 scalar).
// Numerically identical (same dot products, same hh/hl/lh term order).
// All compute blocks are fully allowed (128 | every segment boundary) -> no mask logic.
__global__ __launch_bounds__(256, 2) void gemm_kernel(const short* __restrict__ xhi,
                                                      const short* __restrict__ xlo,
                                                      const short* __restrict__ ehi,
                                                      const short* __restrict__ elo,
                                                      const int* __restrict__ split,
                                                      const float* __restrict__ xx,
                                                      const float* __restrict__ ee,
                                                      float* __restrict__ out,
                                                      float* __restrict__ pmin,
                                                      int*   __restrict__ pidx) {
    __shared__ short Ah[2][CHUNK], Bh[2][CHUNK];   // unit U0 (hi), double-buffered
    __shared__ short Al[2][CHUNK], Bl[2][CHUNK];   // unit U1 (lo), double-buffered
    __shared__ float xxs[BM];
    __shared__ float ees[BN];
    __shared__ float redv[2][BM];
    __shared__ int   redi[2][BM];

    // T1 XCD-aware swizzle (NBLK % 8 == 0 -> bijective): XCD k owns s in [k*640,(k+1)*640)
    const int lin = blockIdx.y * NCB + blockIdx.x;
    const int s_  = (lin & 7) * (NBLK / 8) + (lin >> 3);
    const int bx = s_ % NCB;        // code block 0..39
    const int by = s_ / NCB;        // token block 0..127
    const int m0 = by * BM, n0 = bx * BN;
    const int t = threadIdx.x;

    const int s1 = split[1], s2v = split[2];
    const int tmFirst = (m0 >= s1) + (m0 >= s2v);     // 128-row blocks are modality-uniform
    const int cmod = (n0 < N_SHARED) ? -1 : ((n0 - N_SHARED) >> 10);

    float* dOut = out + D_OFF;

    // fully-masked block: pure BIG fill (nt, lane-contiguous), no GEMM
    if (cmod >= 0 && cmod != tmFirst) {
        f32x4 big = {BIGF, BIGF, BIGF, BIGF};
#pragma unroll
        for (int u = 0; u < 16; ++u) {
            int idx = u * 256 + t;              // 0 .. 4095 f32x4 positions
            int row = idx >> 5, col4 = idx & 31;
            __builtin_nontemporal_store(big,
                (f32x4*)(dOut + (size_t)(m0 + row) * N_CODE + n0) + col4);
        }
        if (t < BM) {
            pmin[(size_t)(m0 + t) * NCB + bx] = BIGF;
            pidx[(size_t)(m0 + t) * NCB + bx] = n0;
        }
        return;
    }

    if (t < BM) xxs[t] = xx[m0 + t];
    else        ees[t - BM] = ee[n0 + (t - BM)];
    __syncthreads();                // drain xx/ee loads so manual vmcnt counts see staging only

    f32x4 acc[4][4] = {};

    const int wid = t >> 6, lane = t & 63;
    const int quad = lane >> 4, ln16 = lane & 15;
    const int wr = (wid >> 1) * 64, wc = (wid & 1) * 64;
    const int qb = quad * BM;

    const short* aHiG = xhi + (size_t)by * NKT * CHUNK;
    const short* aLoG = xlo + (size_t)by * NKT * CHUNK;
    const short* bHiG = ehi + (size_t)bx * NKT * CHUNK;
    const short* bLoG = elo + (size_t)bx * NKT * CHUNK;
    const int tOff = t * 8;                     // shorts (16 B per thread per round)

    auto stageU0 = [&](int kt, int b) {         // 4 glds: Ah, Bh
        const size_t co = (size_t)kt * CHUNK;
#pragma unroll
        for (int p = 0; p < 2; ++p) {
            int o = p * 2048 + tOff;
            __builtin_amdgcn_global_load_lds((g_u32*)(aHiG + co + o), (lds_u32*)&Ah[b][o], 16, 0, 0);
            __builtin_amdgcn_global_load_lds((g_u32*)(bHiG + co + o), (lds_u32*)&Bh[b][o], 16, 0, 0);
        }
    };
    auto stageU1 = [&](int kt, int b) {         // 4 glds: Al, Bl
        const size_t co = (size_t)kt * CHUNK;
#pragma unroll
        for (int p = 0; p < 2; ++p) {
            int o = p * 2048 + tOff;
            __builtin_amdgcn_global_load_lds((g_u32*)(aLoG + co + o), (lds_u32*)&Al[b][o], 16, 0, 0);
            __builtin_amdgcn_global_load_lds((g_u32*)(bLoG + co + o), (lds_u32*)&Bl[b][o], 16, 0, 0);
        }
    };

    // prologue: U0(0), U1(0), U0(1) in flight (12 vmem ops)
    stageU0(0, 0); stageU1(0, 0); stageU0(1, 1);
    int cur = 0;

    // Per tile: phase A needs U0(t) -> wait leaving {U1(t), U0(t+1)} = 8 in flight.
    //           phase B/C need U1(t) -> wait leaving {U0(t+1), U1(t+1)} = 8 in flight.
    // vmcnt hits 0 only in the final tile.
#define TILE(VA, VB, DOU1, DOU2, KT)                                                         \
    {                                                                                        \
        VMW(VA);                                                                             \
        __builtin_amdgcn_s_barrier();                                                        \
        if (DOU1) stageU1((KT) + 1, cur ^ 1);                                                \
        bf16x8 ah[4], bh[4];                                                                 \
        _Pragma("unroll") for (int i = 0; i < 4; ++i)                                        \
            ah[i] = *(const bf16x8*)&Ah[cur][(qb + wr + i * 16 + ln16) * 8];                 \
        _Pragma("unroll") for (int j = 0; j < 4; ++j)                                        \
            bh[j] = *(const bf16x8*)&Bh[cur][(qb + wc + j * 16 + ln16) * 8];                 \
        __builtin_amdgcn_s_setprio(1);                                                       \
        _Pragma("unroll") for (int i = 0; i < 4; ++i)                                        \
            _Pragma("unroll") for (int j = 0; j < 4; ++j)                                    \
                acc[i][j] = __builtin_amdgcn_mfma_f32_16x16x32_bf16(bh[j], ah[i], acc[i][j], 0, 0, 0); \
        __builtin_amdgcn_s_setprio(0);                                                       \
        VMW(VB);                                                                             \
        __builtin_amdgcn_s_barrier();                                                        \
        if (DOU2) stageU0((KT) + 2, cur);                                                    \
        bf16x8 bl[4];                                                                        \
        _Pragma("unroll") for (int j = 0; j < 4; ++j)                                        \
            bl[j] = *(const bf16x8*)&Bl[cur][(qb + wc + j * 16 + ln16) * 8];                 \
        __builtin_amdgcn_s_setprio(1);                                                       \
        _Pragma("unroll") for (int i = 0; i < 4; ++i)                                        \
            _Pragma("unroll") for (int j = 0; j < 4; ++j)                                    \
                acc[i][j] = __builtin_amdgcn_mfma_f32_16x16x32_bf16(bl[j], ah[i], acc[i][j], 0, 0, 0); \
        __builtin_amdgcn_s_setprio(0);                                                       \
        bf16x8 al[4];                                                                        \
        _Pragma("unroll") for (int i = 0; i < 4; ++i)                                        \
            al[i] = *(const bf16x8*)&Al[cur][(qb + wr + i * 16 + ln16) * 8];                 \
        __builtin_amdgcn_s_setprio(1);                                                       \
        _Pragma("unroll") for (int i = 0; i < 4; ++i)                                        \
            _Pragma("unroll") for (int j = 0; j < 4; ++j)                                    \
                acc[i][j] = __builtin_amdgcn_mfma_f32_16x16x32_bf16(bh[j], al[i], acc[i][j], 0, 0, 0); \
        __builtin_amdgcn_s_setprio(0);                                                       \
        cur ^= 1;                                                                            \
    }

    for (int kt = 0; kt < NKT - 2; ++kt)
        TILE(8, 8, true, true, kt);
    TILE(8, 8, true, false, NKT - 2);
    TILE(4, 0, false, false, NKT - 1);
#undef TILE

    // epilogue: d = xx + ee - 2*dot, f32x4 nt-store along row, row-argmin over this block.
    // Swapped C/D layout: token = wr + i*16 + ln16, codes = wc + j*16 + quad*4 + r (r = reg).
#pragma unroll
    for (int i = 0; i < 4; ++i) {
        const int lt = wr + i * 16 + ln16;          // local token row
        const int gt = m0 + lt;
        const float xv = xxs[lt];
        float best = 3.4e38f;
        int bidx = n0;
#pragma unroll
        for (int j = 0; j < 4; ++j) {
            const int cb = wc + j * 16 + quad * 4;  // local code base (x4-aligned)
            f32x4 dv;
#pragma unroll
            for (int r = 0; r < 4; ++r) {
                float v = fmaf(-2.f, acc[i][j][r], xv + ees[cb + r]);
                dv[r] = v;
                if (v < best) { best = v; bidx = n0 + cb + r; }  // ascending code: ties keep lowest
            }
            __builtin_nontemporal_store(dv, (f32x4*)(dOut + (size_t)gt * N_CODE + n0 + cb));
        }
        // reduce across quads (lanes +-16, +-32 share the same token)
#pragma unroll
        for (int s = 16; s < 64; s <<= 1) {
            float ov = __shfl_xor(best, s, 64);
            int   oi = __shfl_xor(bidx, s, 64);
            if (ov < best || (ov == best && oi < bidx)) { best = ov; bidx = oi; }
        }
        if (quad == 0) { redv[wid & 1][lt] = best; redi[wid & 1][lt] = bidx; }
    }
    __syncthreads();
    if (t < BM) {
        float v0 = redv[0][t]; int i0 = redi[0][t];
        float v1 = redv[1][t]; int i1 = redi[1][t];
        if (v1 < v0 || (v1 == v0 && i1 < i0)) { v0 = v1; i0 = i1; }
        pmin[(size_t)(m0 + t) * NCB + bx] = v0;
        pidx[(size_t)(m0 + t) * NCB + bx] = i0;
    }
}

// ---------------- K2: per-token argmin over 40 partials + gather x_q, STE, loss partials ----------------
__global__ __launch_bounds__(256) void gather_kernel(const float* __restrict__ x,
                                                     const float* __restrict__ emb,
                                                     const int* __restrict__ split,
                                                     float* __restrict__ out,
                                                     const float* __restrict__ pmin,
                                                     const int* __restrict__ pidx,
                                                     float* __restrict__ wsLoss) {
    __shared__ float ls[3];
    int t = threadIdx.x, wid = t >> 6, ln = t & 63;
    if (t < 3) ls[t] = 0.f;
    __syncthreads();
    int tok = blockIdx.x * 4 + wid;

    // wave-wide argmin over this token's NCB partials (lanes >= NCB carry sentinels)
    float best = 3.4e38f;
    int bi = 0x7fffffff;
    if (ln < NCB) {
        best = pmin[(size_t)tok * NCB + ln];
        bi   = pidx[(size_t)tok * NCB + ln];
    }
#pragma unroll
    for (int sh = 32; sh; sh >>= 1) {
        float ov = __shfl_xor(best, sh, 64);
        int   oi = __shfl_xor(bi, sh, 64);
        if (ov < best || (ov == best && oi < bi)) { best = ov; bi = oi; }
    }
    if (ln == 0) out[IDX_OFF + tok] = (float)bi;
    int idx = bi;

    f32x4 e  = ((const f32x4*)(emb + (size_t)idx * E_DIM))[ln];
    f32x4 xv = ((const f32x4*)(x + (size_t)tok * E_DIM))[ln];
    f32x4 q;
    float s = 0.f;
#pragma unroll
    for (int c = 0; c < 4; ++c) {
        float d = e[c] - xv[c];
        q[c] = xv[c] + d;               // straight-through: x + (x_q - x)
        s = fmaf(d, d, s);
    }
    __builtin_nontemporal_store(q, (f32x4*)(out + (size_t)tok * E_DIM) + ln);
#pragma unroll
    for (int sh = 32; sh; sh >>= 1) s += __shfl_xor(s, sh, 64);
    if (ln == 0) {
        int mod = (tok >= split[1]) + (tok >= split[2]);
        atomicAdd(&ls[mod], s);
    }
    __syncthreads();
    if (t < 3) wsLoss[blockIdx.x * 3 + t] = ls[t];
}

// ---------------- K3: final loss reduction ----------------
__global__ __launch_bounds__(256) void loss_kernel(const float* __restrict__ wsLoss,
                                                   const int* __restrict__ split,
                                                   float* __restrict__ out, int nblk) {
    __shared__ float red[256];
    float s[3] = {0.f, 0.f, 0.f};
    for (int b = threadIdx.x; b < nblk; b += 256) {
        s[0] += wsLoss[b * 3 + 0];
        s[1] += wsLoss[b * 3 + 1];
        s[2] += wsLoss[b * 3 + 2];
    }
    for (int m = 0; m < 3; ++m) {
        red[threadIdx.x] = s[m];
        __syncthreads();
        for (int st = 128; st; st >>= 1) {
            if (threadIdx.x < st) red[threadIdx.x] += red[threadIdx.x + st];
            __syncthreads();
        }
        if (threadIdx.x == 0) {
            float cnt = (float)(split[m + 1] - split[m]) * (float)E_DIM;
            float a = red[0] / cnt;
            out[QL_OFF + m] = a + 0.25f * a;   // code + beta*commit (numerically equal)
        }
        __syncthreads();
    }
}

extern "C" void kernel_launch(void* const* d_in, const int* in_sizes, int n_in,
                              void* d_out, int out_size, void* d_ws, size_t ws_size,
                              hipStream_t stream) {
    const float* x   = (const float*)d_in[0];
    const float* emb = (const float*)d_in[1];
    const int* split = (const int*)d_in[2];
    float* out = (float*)d_out;

    float* xx     = (float*)d_ws;                          // 16384 f32
    float* ee     = xx + N_TOK;                            // 5120 f32
    float* wsLoss = ee + N_CODE;                           // 4096*3 f32
    float* pmin   = wsLoss + 4096 * 3;                     // 16384*40 f32
    int*   pidx   = (int*)(pmin + (size_t)N_TOK * NCB);    // 16384*40 i32
    short* xhi    = (short*)(pidx + (size_t)N_TOK * NCB);
    short* xlo    = xhi + (size_t)N_TOK * E_DIM;
    short* ehi    = xlo + (size_t)N_TOK * E_DIM;
    short* elo    = ehi + (size_t)N_CODE * E_DIM;
    int nblkGather = N_TOK / 4;            // 4096

    convert_kernel<<<dim3((N_TOK + N_CODE) / 4), dim3(256), 0, stream>>>(x, emb, xx, ee, xhi, xlo, ehi, elo);
    gemm_kernel<<<dim3(NCB, N_TOK / BM), dim3(256), 0, stream>>>(xhi, xlo, ehi, elo, split, xx, ee, out, pmin, pidx);
    gather_kernel<<<dim3(nblkGather), dim3(256), 0, stream>>>(x, emb, split, out, pmin, pidx, wsLoss);
    loss_kernel<<<dim3(1), dim3(256), 0, stream>>>(wsLoss, split, out, nblkGather);
}

// Round 6
// 421.711 us; speedup vs baseline: 1.1822x; 1.0148x over previous
//
#include <hip/hip_runtime.h>
#include <stdint.h>

#define N_TOK    16384
#define E_DIM    256
#define N_CODE   5120
#define N_SHARED 2048
#define BIGF     1e7f

#define BM  128
#define BN  128
#define BK  32
#define NCB (N_CODE / BN)           // 40 column blocks
#define NKT (E_DIM / BK)            // 8 K-tiles
#define CHUNK (BM * BK)             // 4096 shorts = 8 KB per stream per K-tile
#define NBLK (NCB * (N_TOK / BM))   // 5120 blocks, %8 == 0 -> simple XCD swizzle bijective

#define IDX_OFF ((size_t)N_TOK * E_DIM)                    // 4194304
#define D_OFF   (IDX_OFF + N_TOK)                          // 4210688
#define QL_OFF  (D_OFF + (size_t)N_TOK * N_CODE)           // 88096768

typedef float f32x4 __attribute__((ext_vector_type(4)));
typedef short bf16x8 __attribute__((ext_vector_type(8)));
typedef short s16x4 __attribute__((ext_vector_type(4)));

typedef __attribute__((address_space(1))) const unsigned int g_u32;
typedef __attribute__((address_space(3))) unsigned int lds_u32;

__device__ __forceinline__ unsigned short bf16_rn(float f) {
    unsigned u = __float_as_uint(f);
    u += 0x7FFF + ((u >> 16) & 1);          // round-to-nearest-even
    return (unsigned short)(u >> 16);
}
__device__ __forceinline__ float bf16_to_f(unsigned short h) {
    return __uint_as_float(((unsigned)h) << 16);
}

// ---------------- K0: convert to hi/lo bf16 (fragment-swizzled, 128-row tiles) + row norms ----------------
// layout: [tile(128rows)][kt(8)][quad(4)][row(128)][8] -> linear global_load_lds staging
__global__ __launch_bounds__(256) void convert_kernel(const float* __restrict__ x,
                                                      const float* __restrict__ emb,
                                                      float* __restrict__ xx,
                                                      float* __restrict__ ee,
                                                      short* __restrict__ xhi, short* __restrict__ xlo,
                                                      short* __restrict__ ehi, short* __restrict__ elo) {
    int wid = threadIdx.x >> 6, ln = threadIdx.x & 63;
    int row = blockIdx.x * 4 + wid;             // 0 .. 21503
    const float* src; float* nrm; short *hiA, *loA; int rl, tb;
    if (row < N_TOK) {
        src = x + (size_t)row * E_DIM; nrm = xx + row;
        tb = row >> 7; rl = row & 127; hiA = xhi; loA = xlo;
    } else {
        int r = row - N_TOK;
        src = emb + (size_t)r * E_DIM; nrm = ee + r;
        tb = r >> 7; rl = r & 127; hiA = ehi; loA = elo;
    }
    f32x4 v = ((const f32x4*)src)[ln];          // k = ln*4 .. ln*4+3
    float s = v[0]*v[0] + v[1]*v[1] + v[2]*v[2] + v[3]*v[3];
    s16x4 h, l;
#pragma unroll
    for (int c = 0; c < 4; ++c) {
        unsigned short hh = bf16_rn(v[c]);
        h[c] = (short)hh;
        l[c] = (short)bf16_rn(v[c] - bf16_to_f(hh));
    }
    int kt = ln >> 3, q = (ln >> 1) & 3, kl4 = (ln & 1) * 4;
    size_t di = ((((size_t)tb * NKT + kt) * 4 + q) * BM + rl) * 8 + kl4;
    *(s16x4*)&hiA[di] = h;
    *(s16x4*)&loA[di] = l;
#pragma unroll
    for (int sh = 32; sh; sh >>= 1) s += __shfl_xor(s, sh, 64);
    if (ln == 0) *nrm = s;
}

// ---------------- K1: distance GEMM (128x128, single-buffered LDS, 3 blocks/CU) + per-block argmin ----------------
// Round-6: same theory as round 5 (trade the useless double-buffer for occupancy:
// 35 KB LDS -> 3 blocks/CU, per-kt drain stalls hidden by other resident blocks),
// but with the round-0-PROVEN sync structure: __syncthreads() around staging
// (compiler emits the full vmcnt/lgkmcnt drain before s_barrier), no inline-asm waits.
// Retained from round 4: XCD swizzle, swapped-operand epilogue (f32x4 row stores),
// NT stores, identical hh->hl->lh accumulation order (bit-identical outputs).
__global__ __launch_bounds__(256, 3) void gemm_kernel(const short* __restrict__ xhi,
                                                      const short* __restrict__ xlo,
                                                      const short* __restrict__ ehi,
                                                      const short* __restrict__ elo,
                                                      const int* __restrict__ split,
                                                      const float* __restrict__ xx,
                                                      const float* __restrict__ ee,
                                                      float* __restrict__ out,
                                                      float* __restrict__ pmin,
                                                      int*   __restrict__ pidx) {
    __shared__ short Ah[CHUNK], Bh[CHUNK];
    __shared__ short Al[CHUNK], Bl[CHUNK];
    __shared__ float xxs[BM];
    __shared__ float ees[BN];
    __shared__ float redv[2][BM];
    __shared__ int   redi[2][BM];

    // T1 XCD-aware swizzle (NBLK % 8 == 0 -> bijective): XCD k owns s in [k*640,(k+1)*640)
    const int lin = blockIdx.y * NCB + blockIdx.x;
    const int s_  = (lin & 7) * (NBLK / 8) + (lin >> 3);
    const int bx = s_ % NCB;        // code block 0..39
    const int by = s_ / NCB;        // token block 0..127
    const int m0 = by * BM, n0 = bx * BN;
    const int t = threadIdx.x;

    const int s1 = split[1], s2v = split[2];
    const int tmFirst = (m0 >= s1) + (m0 >= s2v);     // 128-row blocks are modality-uniform
    const int cmod = (n0 < N_SHARED) ? -1 : ((n0 - N_SHARED) >> 10);

    float* dOut = out + D_OFF;

    // fully-masked block: pure BIG fill (nt, lane-contiguous), no GEMM
    if (cmod >= 0 && cmod != tmFirst) {
        f32x4 big = {BIGF, BIGF, BIGF, BIGF};
#pragma unroll
        for (int u = 0; u < 16; ++u) {
            int idx = u * 256 + t;              // 0 .. 4095 f32x4 positions
            int row = idx >> 5, col4 = idx & 31;
            __builtin_nontemporal_store(big,
                (f32x4*)(dOut + (size_t)(m0 + row) * N_CODE + n0) + col4);
        }
        if (t < BM) {
            pmin[(size_t)(m0 + t) * NCB + bx] = BIGF;
            pidx[(size_t)(m0 + t) * NCB + bx] = n0;
        }
        return;
    }

    if (t < BM) xxs[t] = xx[m0 + t];
    else        ees[t - BM] = ee[n0 + (t - BM)];

    f32x4 acc[4][4] = {};

    const int wid = t >> 6, lane = t & 63;
    const int quad = lane >> 4, ln16 = lane & 15;
    const int wr = (wid >> 1) * 64, wc = (wid & 1) * 64;
    const int qb = quad * BM;

    const short* aHiG = xhi + (size_t)by * NKT * CHUNK;
    const short* aLoG = xlo + (size_t)by * NKT * CHUNK;
    const short* bHiG = ehi + (size_t)bx * NKT * CHUNK;
    const short* bLoG = elo + (size_t)bx * NKT * CHUNK;
    const int tOff = t * 8;                     // shorts (16 B per thread per round)

    for (int kt = 0; kt < NKT; ++kt) {
        __syncthreads();                        // previous iter's LDS reads done (also covers xxs/ees)
        const size_t co = (size_t)kt * CHUNK;
#pragma unroll
        for (int p = 0; p < 2; ++p) {
            int o = p * 2048 + tOff;
            __builtin_amdgcn_global_load_lds((g_u32*)(aHiG + co + o), (lds_u32*)&Ah[o], 16, 0, 0);
            __builtin_amdgcn_global_load_lds((g_u32*)(bHiG + co + o), (lds_u32*)&Bh[o], 16, 0, 0);
            __builtin_amdgcn_global_load_lds((g_u32*)(aLoG + co + o), (lds_u32*)&Al[o], 16, 0, 0);
            __builtin_amdgcn_global_load_lds((g_u32*)(bLoG + co + o), (lds_u32*)&Bl[o], 16, 0, 0);
        }
        __syncthreads();                        // full drain: all staging loads landed

        // phase 1: hh
        bf16x8 ah[4], bh[4];
#pragma unroll
        for (int i = 0; i < 4; ++i)
            ah[i] = *(const bf16x8*)&Ah[(qb + wr + i * 16 + ln16) * 8];
#pragma unroll
        for (int j = 0; j < 4; ++j)
            bh[j] = *(const bf16x8*)&Bh[(qb + wc + j * 16 + ln16) * 8];
        __builtin_amdgcn_s_setprio(1);
#pragma unroll
        for (int i = 0; i < 4; ++i)
#pragma unroll
            for (int j = 0; j < 4; ++j)
                acc[i][j] = __builtin_amdgcn_mfma_f32_16x16x32_bf16(bh[j], ah[i], acc[i][j], 0, 0, 0);
        __builtin_amdgcn_s_setprio(0);

        // phase 2: hl (A_hi x B_lo) -- same accumulation order as previous rounds
        bf16x8 bl[4];
#pragma unroll
        for (int j = 0; j < 4; ++j)
            bl[j] = *(const bf16x8*)&Bl[(qb + wc + j * 16 + ln16) * 8];
        __builtin_amdgcn_s_setprio(1);
#pragma unroll
        for (int i = 0; i < 4; ++i)
#pragma unroll
            for (int j = 0; j < 4; ++j)
                acc[i][j] = __builtin_amdgcn_mfma_f32_16x16x32_bf16(bl[j], ah[i], acc[i][j], 0, 0, 0);
        __builtin_amdgcn_s_setprio(0);

        // phase 3: lh (A_lo x B_hi)
        bf16x8 al[4];
#pragma unroll
        for (int i = 0; i < 4; ++i)
            al[i] = *(const bf16x8*)&Al[(qb + wr + i * 16 + ln16) * 8];
        __builtin_amdgcn_s_setprio(1);
#pragma unroll
        for (int i = 0; i < 4; ++i)
#pragma unroll
            for (int j = 0; j < 4; ++j)
                acc[i][j] = __builtin_amdgcn_mfma_f32_16x16x32_bf16(bh[j], al[i], acc[i][j], 0, 0, 0);
        __builtin_amdgcn_s_setprio(0);
    }

    // epilogue: d = xx + ee - 2*dot, f32x4 nt-store along row, row-argmin over this block.
    // Swapped C/D layout: token = wr + i*16 + ln16, codes = wc + j*16 + quad*4 + r (r = reg).
#pragma unroll
    for (int i = 0; i < 4; ++i) {
        const int lt = wr + i * 16 + ln16;          // local token row
        const int gt = m0 + lt;
        const float xv = xxs[lt];
        float best = 3.4e38f;
        int bidx = n0;
#pragma unroll
        for (int j = 0; j < 4; ++j) {
            const int cb = wc + j * 16 + quad * 4;  // local code base (x4-aligned)
            f32x4 dv;
#pragma unroll
            for (int r = 0; r < 4; ++r) {
                float v = fmaf(-2.f, acc[i][j][r], xv + ees[cb + r]);
                dv[r] = v;
                if (v < best) { best = v; bidx = n0 + cb + r; }  // ascending code: ties keep lowest
            }
            __builtin_nontemporal_store(dv, (f32x4*)(dOut + (size_t)gt * N_CODE + n0 + cb));
        }
        // reduce across quads (lanes +-16, +-32 share the same token)
#pragma unroll
        for (int s = 16; s < 64; s <<= 1) {
            float ov = __shfl_xor(best, s, 64);
            int   oi = __shfl_xor(bidx, s, 64);
            if (ov < best || (ov == best && oi < bidx)) { best = ov; bidx = oi; }
        }
        if (quad == 0) { redv[wid & 1][lt] = best; redi[wid & 1][lt] = bidx; }
    }
    __syncthreads();
    if (t < BM) {
        float v0 = redv[0][t]; int i0 = redi[0][t];
        float v1 = redv[1][t]; int i1 = redi[1][t];
        if (v1 < v0 || (v1 == v0 && i1 < i0)) { v0 = v1; i0 = i1; }
        pmin[(size_t)(m0 + t) * NCB + bx] = v0;
        pidx[(size_t)(m0 + t) * NCB + bx] = i0;
    }
}

// ---------------- K2: per-token argmin over 40 partials + gather x_q, STE, loss partials ----------------
__global__ __launch_bounds__(256) void gather_kernel(const float* __restrict__ x,
                                                     const float* __restrict__ emb,
                                                     const int* __restrict__ split,
                                                     float* __restrict__ out,
                                                     const float* __restrict__ pmin,
                                                     const int* __restrict__ pidx,
                                                     float* __restrict__ wsLoss) {
    __shared__ float ls[3];
    int t = threadIdx.x, wid = t >> 6, ln = t & 63;
    if (t < 3) ls[t] = 0.f;
    __syncthreads();
    int tok = blockIdx.x * 4 + wid;

    // wave-wide argmin over this token's NCB partials (lanes >= NCB carry sentinels)
    float best = 3.4e38f;
    int bi = 0x7fffffff;
    if (ln < NCB) {
        best = pmin[(size_t)tok * NCB + ln];
        bi   = pidx[(size_t)tok * NCB + ln];
    }
#pragma unroll
    for (int sh = 32; sh; sh >>= 1) {
        float ov = __shfl_xor(best, sh, 64);
        int   oi = __shfl_xor(bi, sh, 64);
        if (ov < best || (ov == best && oi < bi)) { best = ov; bi = oi; }
    }
    if (ln == 0) out[IDX_OFF + tok] = (float)bi;
    int idx = bi;

    f32x4 e  = ((const f32x4*)(emb + (size_t)idx * E_DIM))[ln];
    f32x4 xv = ((const f32x4*)(x + (size_t)tok * E_DIM))[ln];
    f32x4 q;
    float s = 0.f;
#pragma unroll
    for (int c = 0; c < 4; ++c) {
        float d = e[c] - xv[c];
        q[c] = xv[c] + d;               // straight-through: x + (x_q - x)
        s = fmaf(d, d, s);
    }
    __builtin_nontemporal_store(q, (f32x4*)(out + (size_t)tok * E_DIM) + ln);
#pragma unroll
    for (int sh = 32; sh; sh >>= 1) s += __shfl_xor(s, sh, 64);
    if (ln == 0) {
        int mod = (tok >= split[1]) + (tok >= split[2]);
        atomicAdd(&ls[mod], s);
    }
    __syncthreads();
    if (t < 3) wsLoss[blockIdx.x * 3 + t] = ls[t];
}

// ---------------- K3: final loss reduction ----------------
__global__ __launch_bounds__(256) void loss_kernel(const float* __restrict__ wsLoss,
                                                   const int* __restrict__ split,
                                                   float* __restrict__ out, int nblk) {
    __shared__ float red[256];
    float s[3] = {0.f, 0.f, 0.f};
    for (int b = threadIdx.x; b < nblk; b += 256) {
        s[0] += wsLoss[b * 3 + 0];
        s[1] += wsLoss[b * 3 + 1];
        s[2] += wsLoss[b * 3 + 2];
    }
    for (int m = 0; m < 3; ++m) {
        red[threadIdx.x] = s[m];
        __syncthreads();
        for (int st = 128; st; st >>= 1) {
            if (threadIdx.x < st) red[threadIdx.x] += red[threadIdx.x + st];
            __syncthreads();
        }
        if (threadIdx.x == 0) {
            float cnt = (float)(split[m + 1] - split[m]) * (float)E_DIM;
            float a = red[0] / cnt;
            out[QL_OFF + m] = a + 0.25f * a;   // code + beta*commit (numerically equal)
        }
        __syncthreads();
    }
}

extern "C" void kernel_launch(void* const* d_in, const int* in_sizes, int n_in,
                              void* d_out, int out_size, void* d_ws, size_t ws_size,
                              hipStream_t stream) {
    const float* x   = (const float*)d_in[0];
    const float* emb = (const float*)d_in[1];
    const int* split = (const int*)d_in[2];
    float* out = (float*)d_out;

    float* xx     = (float*)d_ws;                          // 16384 f32
    float* ee     = xx + N_TOK;                            // 5120 f32
    float* wsLoss = ee + N_CODE;                           // 4096*3 f32
    float* pmin   = wsLoss + 4096 * 3;                     // 16384*40 f32
    int*   pidx   = (int*)(pmin + (size_t)N_TOK * NCB);    // 16384*40 i32
    short* xhi    = (short*)(pidx + (size_t)N_TOK * NCB);
    short* xlo    = xhi + (size_t)N_TOK * E_DIM;
    short* ehi    = xlo + (size_t)N_TOK * E_DIM;
    short* elo    = ehi + (size_t)N_CODE * E_DIM;
    int nblkGather = N_TOK / 4;            // 4096

    convert_kernel<<<dim3((N_TOK + N_CODE) / 4), dim3(256), 0, stream>>>(x, emb, xx, ee, xhi, xlo, ehi, elo);
    gemm_kernel<<<dim3(NCB, N_TOK / BM), dim3(256), 0, stream>>>(xhi, xlo, ehi, elo, split, xx, ee, out, pmin, pidx);
    gather_kernel<<<dim3(nblkGather), dim3(256), 0, stream>>>(x, emb, split, out, pmin, pidx, wsLoss);
    loss_kernel<<<dim3(1), dim3(256), 0, stream>>>(wsLoss, split, out, nblkGather);
}